// Round 1
// baseline (541.476 us; speedup 1.0000x reference)
//
#include <hip/hip_runtime.h>
#include <math.h>

// Shapes: B=4, S=64, D=64, UNITS=64, ROUTINGS=3
// Inputs: 0 inputs(4,64,64) f32, 1 space(4,4096,4096) f32, 2 bias(4,1) f32,
//         3 W_caps(64,4096) f32, 4 W_time(64,64) f32, 5 W_feat(64,64) f32, 6 b_enc(64,64) f32
// Output: outputs(4,64,64) then updated_space(4,4096,4096), concatenated flat.

// ---------------- K2: u_hat = leakyrelu(inputs * diag(space)) @ W_caps ----------------
// 64 blocks x 256 threads; each block computes 4 rows (b,s) of u_hat[256][4096].
__global__ __launch_bounds__(256) void k_uhat(const float* __restrict__ inputs,
                                              const float* __restrict__ space,
                                              const float* __restrict__ Wc,
                                              float* __restrict__ uhat) {
    __shared__ float cross_s[4][64];
    const int t = threadIdx.x;
    const int r0 = blockIdx.x * 4;
    if (t < 64) {
        #pragma unroll
        for (int r = 0; r < 4; ++r) {
            int row = r0 + r;
            int b = row >> 6, s = row & 63;
            float x = inputs[row * 64 + t];
            // diag[b,s,t] = space[b, s*65, t*65]
            float dg = space[(size_t)(b * 4096 + s * 65) * 4096 + (size_t)(t * 65)];
            float v = x * dg;
            cross_s[r][t] = (v >= 0.f) ? v : 0.2f * v;   // LeakyRelu alpha=0.2
        }
    }
    __syncthreads();
    float4 acc[4][4];
    #pragma unroll
    for (int r = 0; r < 4; ++r)
        #pragma unroll
        for (int k = 0; k < 4; ++k) acc[r][k] = make_float4(0.f, 0.f, 0.f, 0.f);
    const float4* Wc4 = (const float4*)Wc;
    for (int d = 0; d < 64; ++d) {
        float4 w[4];
        #pragma unroll
        for (int k = 0; k < 4; ++k) w[k] = Wc4[d * 1024 + k * 256 + t];
        #pragma unroll
        for (int r = 0; r < 4; ++r) {
            float cr = cross_s[r][d];
            #pragma unroll
            for (int k = 0; k < 4; ++k) {
                acc[r][k].x = fmaf(cr, w[k].x, acc[r][k].x);
                acc[r][k].y = fmaf(cr, w[k].y, acc[r][k].y);
                acc[r][k].z = fmaf(cr, w[k].z, acc[r][k].z);
                acc[r][k].w = fmaf(cr, w[k].w, acc[r][k].w);
            }
        }
    }
    float4* U4 = (float4*)uhat;
    #pragma unroll
    for (int r = 0; r < 4; ++r)
        #pragma unroll
        for (int k = 0; k < 4; ++k)
            U4[(size_t)(r0 + r) * 1024 + k * 256 + t] = acc[r][k];
}

// ---------------- R: one routing iteration. 256 blocks = (b,n), 256 threads ----------------
// c[n,i] = exp(brt[n,i]) / colsum_prev[b,i]   (iter 0: c = 1/64)
// o[n,v] = squash( sum_i c[n,i] * uhat[b,i,n*64+v] )
// iter<2: brt[n,i] += sum_v o[n,v]*uhat[b,i,n*64+v]; atomicAdd colsum_next[b,i] += exp(brt_new)
// iter==2: filt[b,n,v] = o[n,v]
__global__ __launch_bounds__(256) void k_route(const float* __restrict__ uhat,
                                               float* __restrict__ brt,
                                               const float* __restrict__ colsum_prev,
                                               float* __restrict__ colsum_next,
                                               float* __restrict__ filt,
                                               int iter) {
    __shared__ float Us[64][65];
    __shared__ float c_s[64];
    __shared__ float o_s[64];
    const int t = threadIdx.x;
    const int b = blockIdx.x >> 6;
    const int n = blockIdx.x & 63;
    const float* base = uhat + (size_t)b * 262144 + n * 64;
    #pragma unroll
    for (int k = 0; k < 4; ++k) {
        int fidx = t + k * 256;             // [0,1024) float4s of the 64x64 slice
        int i = fidx >> 4, v4 = fidx & 15;
        float4 val = *(const float4*)(base + (size_t)i * 4096 + v4 * 4);
        Us[i][v4 * 4 + 0] = val.x;
        Us[i][v4 * 4 + 1] = val.y;
        Us[i][v4 * 4 + 2] = val.z;
        Us[i][v4 * 4 + 3] = val.w;
    }
    float r_brt = 0.f;
    if (t < 64) {
        if (iter == 0) {
            c_s[t] = 1.0f / 64.0f;          // softmax of zeros
        } else {
            r_brt = brt[(size_t)(b * 64 + n) * 64 + t];
            c_s[t] = expf(r_brt) / colsum_prev[b * 64 + t];
        }
    }
    __syncthreads();
    if (t < 64) {
        float acc = 0.f;
        #pragma unroll 8
        for (int i = 0; i < 64; ++i) acc += c_s[i] * Us[i][t];
        float sq = acc * acc;
        #pragma unroll
        for (int m = 32; m >= 1; m >>= 1) sq += __shfl_xor(sq, m, 64);
        float factor = (sq / (1.0f + sq)) / sqrtf(sq + 1e-7f);  // squash
        o_s[t] = acc * factor;
    }
    __syncthreads();
    if (t < 64) {
        if (iter < 2) {
            float u = 0.f;
            #pragma unroll 8
            for (int v = 0; v < 64; ++v) u += o_s[v] * Us[t][v];
            float bnew = r_brt + u;
            brt[(size_t)(b * 64 + n) * 64 + t] = bnew;
            atomicAdd(colsum_next + b * 64 + t, expf(bnew));
        } else {
            filt[(size_t)(b * 64 + n) * 64 + t] = o_s[t];
        }
    }
}

// ---------------- Kenc: outputs = relu(filt x W_time x W_feat + b_enc); scale[b] ----------------
// 4 blocks (one per b) x 256 threads
__global__ __launch_bounds__(256) void k_enc(const float* __restrict__ inputs,
                                             const float* __restrict__ space,
                                             const float* __restrict__ bias,
                                             const float* __restrict__ Wt,
                                             const float* __restrict__ Wf,
                                             const float* __restrict__ benc,
                                             const float* __restrict__ filt,
                                             float* __restrict__ out,
                                             float* __restrict__ scale) {
    __shared__ float f_s[64][65];
    __shared__ float t_s[64][65];
    const int t = threadIdx.x;
    const int b = blockIdx.x;
    #pragma unroll
    for (int k = 0; k < 16; ++k) {
        int idx = t + k * 256;
        f_s[idx >> 6][idx & 63] = filt[b * 4096 + idx];
    }
    __syncthreads();
    // tmp[s,v] = sum_u filt[u,v] * W_time[u,s]
    #pragma unroll
    for (int k = 0; k < 16; ++k) {
        int idx = t + k * 256;
        int s = idx >> 6, v = idx & 63;
        float acc = 0.f;
        #pragma unroll 8
        for (int u = 0; u < 64; ++u) acc += f_s[u][v] * Wt[u * 64 + s];
        t_s[s][v] = acc;
    }
    __syncthreads();
    // out[s,d] = relu(sum_v tmp[s,v]*W_feat[v,d] + b_enc[s,d])
    #pragma unroll
    for (int k = 0; k < 16; ++k) {
        int idx = t + k * 256;
        int s = idx >> 6, d = idx & 63;
        float acc = benc[idx];
        #pragma unroll 8
        for (int v = 0; v < 64; ++v) acc += t_s[s][v] * Wf[v * 64 + d];
        out[b * 4096 + idx] = fmaxf(acc, 0.f);
    }
    // scale[b] = tanh(max_i |space[b,0,4095] - inputs[b,i,63]| - bias[b]) / sqrt(2)
    if (t < 64) {
        float ideal00 = space[(size_t)b * 16777216 + 4095];
        float m = fabsf(ideal00 - inputs[b * 4096 + t * 64 + 63]);
        #pragma unroll
        for (int mm = 32; mm >= 1; mm >>= 1) m = fmaxf(m, __shfl_xor(m, mm, 64));
        if (t == 0) scale[b] = tanhf(m - bias[b]) * 0.70710678118654752f;
    }
}

// ---------------- K4: updated_space = space + scale[b]*outputs[b,i,j]*inputs[b,p,q] ----------------
// 65536 blocks x 256 threads; one float4 per thread, pure streaming.
__global__ __launch_bounds__(256) void k_update(const float* __restrict__ space,
                                                const float* __restrict__ inputs,
                                                const float* __restrict__ outs,
                                                const float* __restrict__ scale,
                                                float* __restrict__ out_space) {
    const int idx = blockIdx.x * 256 + threadIdx.x;   // float4 index < 16,777,216
    const int b = idx >> 22;
    const int rem = idx & 4194303;
    const int r = rem >> 10;          // row in [0,4096): r = i*64+p
    const int c4 = rem & 1023;        // float4 col: c = j*64+q, j=c4>>4, q=(c4&15)*4
    const int i = r >> 6, p = r & 63;
    const int j = c4 >> 4, q4 = c4 & 15;
    const float f = scale[b] * outs[(b << 12) + (i << 6) + j];
    const float4 in4 = *(const float4*)(inputs + (b << 12) + (p << 6) + (q4 << 2));
    const float4 sp4 = ((const float4*)space)[idx];
    float4 o;
    o.x = fmaf(f, in4.x, sp4.x);
    o.y = fmaf(f, in4.y, sp4.y);
    o.z = fmaf(f, in4.z, sp4.z);
    o.w = fmaf(f, in4.w, sp4.w);
    ((float4*)out_space)[idx] = o;
}

extern "C" void kernel_launch(void* const* d_in, const int* in_sizes, int n_in,
                              void* d_out, int out_size, void* d_ws, size_t ws_size,
                              hipStream_t stream) {
    (void)in_sizes; (void)n_in; (void)out_size; (void)ws_size;
    const float* inputs = (const float*)d_in[0];
    const float* space  = (const float*)d_in[1];
    const float* bias   = (const float*)d_in[2];
    const float* Wc     = (const float*)d_in[3];
    const float* Wt     = (const float*)d_in[4];
    const float* Wf     = (const float*)d_in[5];
    const float* benc   = (const float*)d_in[6];
    float* out = (float*)d_out;
    float* ws  = (float*)d_ws;

    // ws layout (floats): scale@0[4], colsum1@64[256], colsum2@320[256],
    //                     brt@1024[16384], filt@17408[16384]  (~135 KB total)
    float* scale   = ws;
    float* colsum1 = ws + 64;
    float* colsum2 = ws + 320;
    float* brt     = ws + 1024;
    float* filt    = ws + 17408;
    // u_hat (4 MB) scratched into the updated_space output region;
    // k_update overwrites it afterwards and never reads out_space.
    float* uhat = out + 16384;
    float* out_space = out + 16384;

    hipMemsetAsync(colsum1, 0, 512 * sizeof(float), stream);  // colsum1+colsum2
    k_uhat<<<64, 256, 0, stream>>>(inputs, space, Wc, uhat);
    k_route<<<256, 256, 0, stream>>>(uhat, brt, nullptr, colsum1, filt, 0);
    k_route<<<256, 256, 0, stream>>>(uhat, brt, colsum1, colsum2, filt, 1);
    k_route<<<256, 256, 0, stream>>>(uhat, brt, colsum2, nullptr, filt, 2);
    k_enc<<<4, 256, 0, stream>>>(inputs, space, bias, Wt, Wf, benc, filt, out, scale);
    k_update<<<65536, 256, 0, stream>>>(space, inputs, out, scale, out_space);
}

// Round 2
// 540.582 us; speedup vs baseline: 1.0017x; 1.0017x over previous
//
#include <hip/hip_runtime.h>
#include <math.h>

// Shapes: B=4, S=64, D=64, UNITS=64, ROUTINGS=3
// Inputs: 0 inputs(4,64,64) f32, 1 space(4,4096,4096) f32, 2 bias(4,1) f32,
//         3 W_caps(64,4096) f32, 4 W_time(64,64) f32, 5 W_feat(64,64) f32, 6 b_enc(64,64) f32
// Output: outputs(4,64,64) then updated_space(4,4096,4096), concatenated flat.

typedef float f32x4 __attribute__((ext_vector_type(4)));

// ---------------- K2: u_hat = leakyrelu(inputs * diag(space)) @ W_caps ----------------
// 128 blocks x 256 threads; each block computes 2 rows (b,s) of u_hat[256][4096].
// Block 0 also zero-inits the colsum accumulators (replaces a memset dispatch).
__global__ __launch_bounds__(256) void k_uhat(const float* __restrict__ inputs,
                                              const float* __restrict__ space,
                                              const float* __restrict__ Wc,
                                              float* __restrict__ uhat,
                                              float* __restrict__ colsum) {
    __shared__ float cross_s[2][64];
    const int t = threadIdx.x;
    const int r0 = blockIdx.x * 2;
    if (blockIdx.x == 0) {          // zero colsum1+colsum2 (512 floats)
        colsum[t] = 0.f;
        colsum[t + 256] = 0.f;
    }
    if (t < 128) {
        int r = r0 + (t >> 6);
        int lane = t & 63;
        int b = r >> 6, s = r & 63;
        float x = inputs[r * 64 + lane];
        // diag[b,s,lane] = space[b, s*65, lane*65]
        float dg = space[(size_t)(b * 4096 + s * 65) * 4096 + (size_t)(lane * 65)];
        float v = x * dg;
        cross_s[t >> 6][lane] = (v >= 0.f) ? v : 0.2f * v;   // LeakyRelu alpha=0.2
    }
    __syncthreads();
    f32x4 acc[2][4];
    #pragma unroll
    for (int r = 0; r < 2; ++r)
        #pragma unroll
        for (int k = 0; k < 4; ++k) acc[r][k] = (f32x4)(0.f);
    const f32x4* Wc4 = (const f32x4*)Wc;
    for (int d = 0; d < 64; ++d) {
        f32x4 w[4];
        #pragma unroll
        for (int k = 0; k < 4; ++k) w[k] = Wc4[d * 1024 + k * 256 + t];
        #pragma unroll
        for (int r = 0; r < 2; ++r) {
            float cr = cross_s[r][d];
            #pragma unroll
            for (int k = 0; k < 4; ++k) acc[r][k] += cr * w[k];
        }
    }
    f32x4* U4 = (f32x4*)uhat;
    #pragma unroll
    for (int r = 0; r < 2; ++r)
        #pragma unroll
        for (int k = 0; k < 4; ++k)
            U4[(size_t)(r0 + r) * 1024 + k * 256 + t] = acc[r][k];
}

// ---------------- R: one routing iteration. 256 blocks = (b,n), 256 threads ----------------
// c[n,i] = exp(brt[n,i]) / colsum_prev[b,i]   (iter 0: c = 1/64)
// o[n,v] = squash( sum_i c[n,i] * uhat[b,i,n*64+v] )
// iter<2: brt[n,i] += sum_v o[n,v]*uhat[b,i,n*64+v]; atomicAdd colsum_next[b,i] += exp(brt_new)
// iter==2: filt[b,n,v] = o[n,v]
__global__ __launch_bounds__(256) void k_route(const float* __restrict__ uhat,
                                               float* __restrict__ brt,
                                               const float* __restrict__ colsum_prev,
                                               float* __restrict__ colsum_next,
                                               float* __restrict__ filt,
                                               int iter) {
    __shared__ float Us[64][65];
    __shared__ float c_s[64];
    __shared__ float o_s[64];
    const int t = threadIdx.x;
    const int b = blockIdx.x >> 6;
    const int n = blockIdx.x & 63;
    const float* base = uhat + (size_t)b * 262144 + n * 64;
    #pragma unroll
    for (int k = 0; k < 4; ++k) {
        int fidx = t + k * 256;             // [0,1024) float4s of the 64x64 slice
        int i = fidx >> 4, v4 = fidx & 15;
        float4 val = *(const float4*)(base + (size_t)i * 4096 + v4 * 4);
        Us[i][v4 * 4 + 0] = val.x;
        Us[i][v4 * 4 + 1] = val.y;
        Us[i][v4 * 4 + 2] = val.z;
        Us[i][v4 * 4 + 3] = val.w;
    }
    float r_brt = 0.f;
    if (t < 64) {
        if (iter == 0) {
            c_s[t] = 1.0f / 64.0f;          // softmax of zeros
        } else {
            r_brt = brt[(size_t)(b * 64 + n) * 64 + t];
            c_s[t] = expf(r_brt) / colsum_prev[b * 64 + t];
        }
    }
    __syncthreads();
    if (t < 64) {
        float acc = 0.f;
        #pragma unroll 8
        for (int i = 0; i < 64; ++i) acc += c_s[i] * Us[i][t];
        float sq = acc * acc;
        #pragma unroll
        for (int m = 32; m >= 1; m >>= 1) sq += __shfl_xor(sq, m, 64);
        float factor = (sq / (1.0f + sq)) / sqrtf(sq + 1e-7f);  // squash
        o_s[t] = acc * factor;
    }
    __syncthreads();
    if (t < 64) {
        if (iter < 2) {
            float u = 0.f;
            #pragma unroll 8
            for (int v = 0; v < 64; ++v) u += o_s[v] * Us[t][v];
            float bnew = r_brt + u;
            brt[(size_t)(b * 64 + n) * 64 + t] = bnew;
            atomicAdd(colsum_next + b * 64 + t, expf(bnew));
        } else {
            filt[(size_t)(b * 64 + n) * 64 + t] = o_s[t];
        }
    }
}

// ---------------- Kenc: outputs = relu(filt x W_time x W_feat + b_enc); scale[b] ----------------
// 4 blocks (one per b) x 256 threads
__global__ __launch_bounds__(256) void k_enc(const float* __restrict__ inputs,
                                             const float* __restrict__ space,
                                             const float* __restrict__ bias,
                                             const float* __restrict__ Wt,
                                             const float* __restrict__ Wf,
                                             const float* __restrict__ benc,
                                             const float* __restrict__ filt,
                                             float* __restrict__ out,
                                             float* __restrict__ scale) {
    __shared__ float f_s[64][65];
    __shared__ float t_s[64][65];
    const int t = threadIdx.x;
    const int b = blockIdx.x;
    #pragma unroll
    for (int k = 0; k < 16; ++k) {
        int idx = t + k * 256;
        f_s[idx >> 6][idx & 63] = filt[b * 4096 + idx];
    }
    __syncthreads();
    // tmp[s,v] = sum_u filt[u,v] * W_time[u,s]
    #pragma unroll
    for (int k = 0; k < 16; ++k) {
        int idx = t + k * 256;
        int s = idx >> 6, v = idx & 63;
        float acc = 0.f;
        #pragma unroll 8
        for (int u = 0; u < 64; ++u) acc += f_s[u][v] * Wt[u * 64 + s];
        t_s[s][v] = acc;
    }
    __syncthreads();
    // out[s,d] = relu(sum_v tmp[s,v]*W_feat[v,d] + b_enc[s,d])
    #pragma unroll
    for (int k = 0; k < 16; ++k) {
        int idx = t + k * 256;
        int s = idx >> 6, d = idx & 63;
        float acc = benc[idx];
        #pragma unroll 8
        for (int v = 0; v < 64; ++v) acc += t_s[s][v] * Wf[v * 64 + d];
        out[b * 4096 + idx] = fmaxf(acc, 0.f);
    }
    // scale[b] = tanh(max_i |space[b,0,4095] - inputs[b,i,63]| - bias[b]) / sqrt(2)
    if (t < 64) {
        float ideal00 = space[(size_t)b * 16777216 + 4095];
        float m = fabsf(ideal00 - inputs[b * 4096 + t * 64 + 63]);
        #pragma unroll
        for (int mm = 32; mm >= 1; mm >>= 1) m = fmaxf(m, __shfl_xor(m, mm, 64));
        if (t == 0) scale[b] = tanhf(m - bias[b]) * 0.70710678118654752f;
    }
}

// ---------------- K4: updated_space = space + scale[b]*outputs[b,i,j]*inputs[b,p,q] ----------------
// 65536 blocks x 256 threads; one float4 per thread, pure streaming.
// Cached read of space (likely L3-resident from the harness's d_in restore copy);
// nontemporal store of out_space so the write stream doesn't evict those L3 lines.
__global__ __launch_bounds__(256) void k_update(const float* __restrict__ space,
                                                const float* __restrict__ inputs,
                                                const float* __restrict__ outs,
                                                const float* __restrict__ scale,
                                                float* __restrict__ out_space) {
    const int idx = blockIdx.x * 256 + threadIdx.x;   // float4 index < 16,777,216
    const int b = idx >> 22;
    const int rem = idx & 4194303;
    const int r = rem >> 10;          // row in [0,4096): r = i*64+p
    const int c4 = rem & 1023;        // float4 col: c = j*64+q, j=c4>>4, q=(c4&15)*4
    const int i = r >> 6, p = r & 63;
    const int j = c4 >> 4, q4 = c4 & 15;
    const float f = scale[b] * outs[(b << 12) + (i << 6) + j];
    const f32x4 in4 = *(const f32x4*)(inputs + (b << 12) + (p << 6) + (q4 << 2));
    const f32x4 sp4 = ((const f32x4*)space)[idx];
    f32x4 o = sp4 + f * in4;
    __builtin_nontemporal_store(o, (f32x4*)out_space + idx);
}

extern "C" void kernel_launch(void* const* d_in, const int* in_sizes, int n_in,
                              void* d_out, int out_size, void* d_ws, size_t ws_size,
                              hipStream_t stream) {
    (void)in_sizes; (void)n_in; (void)out_size; (void)ws_size;
    const float* inputs = (const float*)d_in[0];
    const float* space  = (const float*)d_in[1];
    const float* bias   = (const float*)d_in[2];
    const float* Wc     = (const float*)d_in[3];
    const float* Wt     = (const float*)d_in[4];
    const float* Wf     = (const float*)d_in[5];
    const float* benc   = (const float*)d_in[6];
    float* out = (float*)d_out;
    float* ws  = (float*)d_ws;

    // ws layout (floats): scale@0[4], colsum1@64[256], colsum2@320[256],
    //                     brt@1024[16384], filt@17408[16384]  (~135 KB total)
    float* scale   = ws;
    float* colsum1 = ws + 64;
    float* colsum2 = ws + 320;
    float* brt     = ws + 1024;
    float* filt    = ws + 17408;
    // u_hat (4 MB) scratched into the updated_space output region;
    // k_update overwrites it afterwards and never reads out_space.
    float* uhat = out + 16384;
    float* out_space = out + 16384;

    k_uhat<<<128, 256, 0, stream>>>(inputs, space, Wc, uhat, colsum1);
    k_route<<<256, 256, 0, stream>>>(uhat, brt, nullptr, colsum1, filt, 0);
    k_route<<<256, 256, 0, stream>>>(uhat, brt, colsum1, colsum2, filt, 1);
    k_route<<<256, 256, 0, stream>>>(uhat, brt, colsum2, nullptr, filt, 2);
    k_enc<<<4, 256, 0, stream>>>(inputs, space, bias, Wt, Wf, benc, filt, out, scale);
    k_update<<<65536, 256, 0, stream>>>(space, inputs, out, scale, out_space);
}